// Round 3
// baseline (2676.766 us; speedup 1.0000x reference)
//
#include <hip/hip_runtime.h>

#define DTC 0.02f
#define INV_DT_SKIP 2.5f            // 1/(0.02*20)
#define NBLK 250
#define NSTEP 50

typedef __attribute__((ext_vector_type(8))) __bf16 bf16x8;
typedef __attribute__((ext_vector_type(4))) float f32x4;
typedef __attribute__((ext_vector_type(8))) unsigned short us8;

__device__ inline unsigned short f2bf(float x) {        // RNE fp32->bf16
    unsigned u = __float_as_uint(x);
    unsigned r = u + 0x7FFF + ((u >> 16) & 1u);
    return (unsigned short)(r >> 16);
}
__device__ inline float bf2f(unsigned short h) {
    return __uint_as_float(((unsigned)h) << 16);
}

// ---------------------------------------------------------------------------
// Neumann inverses (verified rounds 1-2). inv1 = (I-dt*Ap)^-1,
// inv2 = (3I-2dt*Ap)^-1.
// ---------------------------------------------------------------------------
__global__ __launch_bounds__(256) void kinv(const float* __restrict__ Ap,
                                            float* __restrict__ inv1,
                                            float* __restrict__ inv2) {
    const int t = threadIdx.x;
    const float coef  = (blockIdx.x == 0) ? DTC : (2.0f * DTC / 3.0f);
    const float scale = (blockIdx.x == 0) ? 1.0f : (1.0f / 3.0f);
    float* outp = (blockIdx.x == 0) ? inv1 : inv2;

    __shared__ float ET[64 * 68];
    __shared__ float XA[64 * 68];
    __shared__ float XB[64 * 68];

    for (int idx = t; idx < 4096; idx += 256) {
        int r = idx >> 6, c = idx & 63;
        float e = coef * Ap[idx];
        ET[c * 68 + r] = e;
        XA[r * 68 + c] = ((r == c) ? 1.0f : 0.0f) + e;
    }
    __syncthreads();

    const int rr = (t >> 4) << 2;
    const int cc = (t & 15) << 2;
    float* bufs[2] = {XA, XB};
    for (int it = 0; it < 3; it++) {
        const float* Xin = bufs[it & 1];
        float* Xout = bufs[(it + 1) & 1];
        float acc[4][4];
        #pragma unroll
        for (int i = 0; i < 4; i++)
            #pragma unroll
            for (int j = 0; j < 4; j++)
                acc[i][j] = ((rr + i) == (cc + j)) ? 1.0f : 0.0f;
        for (int k = 0; k < 64; k++) {
            float4 e4 = *(const float4*)&ET[k * 68 + rr];
            float4 x4 = *(const float4*)&Xin[k * 68 + cc];
            float ev[4] = {e4.x, e4.y, e4.z, e4.w};
            float xv[4] = {x4.x, x4.y, x4.z, x4.w};
            #pragma unroll
            for (int i = 0; i < 4; i++)
                #pragma unroll
                for (int j = 0; j < 4; j++)
                    acc[i][j] += ev[i] * xv[j];
        }
        __syncthreads();
        #pragma unroll
        for (int i = 0; i < 4; i++)
            #pragma unroll
            for (int j = 0; j < 4; j++)
                Xout[(rr + i) * 68 + cc + j] = acc[i][j];
        __syncthreads();
    }
    const float* Xf = bufs[1];
    for (int idx = t; idx < 4096; idx += 256) {
        int r = idx >> 6, c = idx & 63;
        outp[idx] = scale * Xf[r * 68 + c];
    }
}

// ---------------------------------------------------------------------------
// Zero the grid-barrier counter and the three F accumulation buffers.
// (ws is poisoned 0xAA before every timed launch.)
// ---------------------------------------------------------------------------
__global__ __launch_bounds__(256) void kzero(float* __restrict__ F,
                                             unsigned* __restrict__ cnt) {
    const int t = threadIdx.x;
    for (int i = t; i < 3 * 2048; i += 256) F[i] = 0.f;
    if (t == 0) *cnt = 0u;
}

// ---------------------------------------------------------------------------
// Monotone-counter grid barrier. Requires all NBLK blocks resident
// (LDS 119KB -> 1 block/CU, 250 <= 256 CUs). Each thread fences its own
// stores, leader arrive-adds and spins on the agent-scope counter.
// ---------------------------------------------------------------------------
__device__ inline void gridbar(unsigned* cnt, unsigned target) {
    __threadfence();
    __syncthreads();
    if (threadIdx.x == 0) {
        __hip_atomic_fetch_add(cnt, 1u, __ATOMIC_ACQ_REL, __HIP_MEMORY_SCOPE_AGENT);
        while (__hip_atomic_load(cnt, __ATOMIC_ACQUIRE, __HIP_MEMORY_SCOPE_AGENT) < target)
            __builtin_amdgcn_s_sleep(1);
        __threadfence();
    }
    __syncthreads();
}

// ---------------------------------------------------------------------------
// Persistent kernel: all 50 steps, one grid barrier per step.
// Phase A (per wave, round-2 verified pipeline): z = a@W^T hi/lo bf16 MFMA,
// f = u*dx+v*dy, LDS C->A relayout, proj MFMA vs P frags, block reduce,
// atomicAdd into F[k%3]. Phase B (redundant per block): f = -F, BDF2 r,
// a_next = r/3 + r@S^T via hi/lo MFMA (S = inv2 - I/3, bf16; waves 0-1),
// step 0 uses fp32 LDS matvec with inv1.
// F[(k+1)%3] is zeroed in phase A of step k: its last readers were phase B
// of step k-2, which every block finished before barrier k-1 (program
// order), and barrier k separates the zeroing from step k+1's adds.
// ---------------------------------------------------------------------------
__global__ __launch_bounds__(512, 2)
void kmain(const float* __restrict__ state,
           const float* __restrict__ Wu,
           const float* __restrict__ Wv,
           const float* __restrict__ Pp,
           const float* __restrict__ inv1,
           const float* __restrict__ inv2,
           float* __restrict__ F,
           unsigned* __restrict__ cnt,
           float* __restrict__ out) {
    const int t = threadIdx.x;
    const int l = t & 63;
    const int w = t >> 6;                 // wave 0..7
    const int blk = blockIdx.x;

    __shared__ float Ab[3][2176];         // a triple buffer, 32 rows x 68
    __shared__ float fb[8][16][36];       // per-wave f tile (K=32, zero-padded)
    __shared__ float red[8][1024];        // per-wave proj partials
    __shared__ float invL[64 * 65];       // inv1 for step-0 scalar matvec
    __shared__ float fpp[2][2048];        // f ping-pong (f_cur / f_prev)
    __shared__ float rbuf[32 * 68];       // r, padded stride 68

    // ---- startup: state -> Ab[0], inv1 -> invL, zero fb ----
    for (int i = t; i < 2048; i += 512) Ab[0][(i >> 6) * 68 + (i & 63)] = state[i];
    for (int i = t; i < 4096; i += 512) invL[(i >> 6) * 65 + (i & 63)] = inv1[i];
    for (int i = t; i < 8 * 16 * 36; i += 512) ((float*)fb)[i] = 0.f;

    // ---- wave tile mapping (round-2 verified) ----
    const int gw = blk * 8 + w;           // 0..1999
    const int tile = gw >> 1;             // 16-group tile 0..999
    const int mt = gw & 1;                // batch mtile
    const int net = tile >= 500;
    const int tn = net ? tile - 500 : tile;
    const int half = tile & 1;
    const int gc = tile >> 1;
    const float* W = net ? Wv : Wu;
    const int nr = l & 15;
    const int c0 = (l >> 4) << 3;

    // ---- preload all fragments into registers (held across the loop) ----
    bf16x8 wf[4][2], pf[4], sf[4][2];
    #pragma unroll
    for (int rb = 0; rb < 4; rb++)
        #pragma unroll
        for (int kt = 0; kt < 2; kt++) {
            const float* s = W + (size_t)(rb * 8000 + tn * 16 + nr) * 64 + kt * 32 + c0;
            us8 o;
            #pragma unroll
            for (int j = 0; j < 8; j++) o[j] = f2bf(s[j]);
            wf[rb][kt] = __builtin_bit_cast(bf16x8, o);
        }
    #pragma unroll
    for (int pt = 0; pt < 4; pt++) {
        const float* s = Pp + (size_t)(pt * 16 + nr) * 16000 + gc * 32 + c0;
        us8 o;
        #pragma unroll
        for (int j = 0; j < 8; j++) o[j] = f2bf(s[j]);
        pf[pt] = __builtin_bit_cast(bf16x8, o);
    }
    #pragma unroll
    for (int pt = 0; pt < 4; pt++)          // S = inv2 - I/3 (B-frag layout)
        #pragma unroll
        for (int kt = 0; kt < 2; kt++) {
            int p = pt * 16 + nr;
            const float* s = inv2 + (size_t)p * 64 + kt * 32 + c0;
            us8 o;
            #pragma unroll
            for (int j = 0; j < 8; j++) {
                float v = s[j] - ((p == kt * 32 + c0 + j) ? (1.0f / 3.0f) : 0.0f);
                o[j] = f2bf(v);
            }
            sf[pt][kt] = __builtin_bit_cast(bf16x8, o);
        }
    __syncthreads();

    int ia_prev = 2, ia_cur = 0, ia_next = 1;
    int ifc = 0;

    for (int k = 0; k < NSTEP; k++) {
        // ================= phase A: rhs partials =================
        float* Fz = F + ((k + 1) % 3) * 2048;     // zero two-steps-ahead buffer
        for (int i = t; i < 2048; i += 512) Fz[i] = 0.f;

        bf16x8 ahi[2], alo[2];
        {
            const float* ac = Ab[ia_cur];
            int m = mt * 16 + nr;
            #pragma unroll
            for (int kt = 0; kt < 2; kt++) {
                us8 hv, lv;
                #pragma unroll
                for (int j = 0; j < 8; j++) {
                    float x = ac[m * 68 + kt * 32 + c0 + j];
                    unsigned short h = f2bf(x);
                    hv[j] = h;
                    lv[j] = f2bf(x - bf2f(h));
                }
                ahi[kt] = __builtin_bit_cast(bf16x8, hv);
                alo[kt] = __builtin_bit_cast(bf16x8, lv);
            }
        }

        f32x4 z[4];
        #pragma unroll
        for (int rb = 0; rb < 4; rb++) {
            f32x4 acc = {0.f, 0.f, 0.f, 0.f};
            #pragma unroll
            for (int kt = 0; kt < 2; kt++) {
                acc = __builtin_amdgcn_mfma_f32_16x16x32_bf16(ahi[kt], wf[rb][kt], acc, 0, 0, 0);
                acc = __builtin_amdgcn_mfma_f32_16x16x32_bf16(alo[kt], wf[rb][kt], acc, 0, 0, 0);
            }
            z[rb] = acc;
        }

        {
            int col = l & 15, q = l >> 4;
            #pragma unroll
            for (int r = 0; r < 4; r++) {
                float f = z[0][r] * z[2][r] + z[1][r] * z[3][r];
                fb[w][q * 4 + r][half * 16 + col] = f;
            }
        }
        __syncthreads();

        bf16x8 ff;
        {
            us8 fv;
            #pragma unroll
            for (int j = 0; j < 8; j++) fv[j] = f2bf(fb[w][nr][c0 + j]);
            ff = __builtin_bit_cast(bf16x8, fv);
        }

        {
            int col = l & 15, q = l >> 4;
            #pragma unroll
            for (int pt = 0; pt < 4; pt++) {
                f32x4 r2 = {0.f, 0.f, 0.f, 0.f};
                r2 = __builtin_amdgcn_mfma_f32_16x16x32_bf16(ff, pf[pt], r2, 0, 0, 0);
                #pragma unroll
                for (int r = 0; r < 4; r++)
                    red[w][(q * 4 + r) * 64 + pt * 16 + col] = r2[r];
            }
        }
        __syncthreads();

        float* Fk = F + (k % 3) * 2048;
        for (int i = t; i < 2048; i += 512) {
            int b = i >> 6, p = i & 63;
            int mtb = b >> 4, bl = b & 15;
            float s = red[0 + mtb][bl * 64 + p] + red[2 + mtb][bl * 64 + p]
                    + red[4 + mtb][bl * 64 + p] + red[6 + mtb][bl * 64 + p];
            atomicAdd(&Fk[i], s);
        }

        gridbar(cnt, (unsigned)(NBLK * (k + 1)));

        // ================= phase B: update (redundant per block) =================
        float* fc = fpp[ifc];
        const float* fp = fpp[ifc ^ 1];
        for (int i = t; i < 2048; i += 512) {
            float s = __hip_atomic_load(&Fk[i], __ATOMIC_RELAXED, __HIP_MEMORY_SCOPE_AGENT);
            float f = -s;
            fc[i] = f;
            int row = (i >> 6) * 68 + (i & 63);
            float av = Ab[ia_cur][row];
            float rv = (k == 0) ? (av + DTC * f)
                                : (4.f * av - Ab[ia_prev][row]
                                   + 4.f * DTC * f - 2.f * DTC * fp[i]);
            rbuf[row] = rv;
        }
        __syncthreads();

        if (k == 0) {
            // fp32 scalar matvec with inv1 (once): a1 = inv1 @ r
            int p = t & 63;
            int b0 = (t >> 6) * 4;
            #pragma unroll
            for (int j = 0; j < 4; j++) {
                int b = b0 + j;
                float acc = 0.f;
                const float* iv = &invL[p * 65];
                const float* rr = &rbuf[b * 68];
                #pragma unroll 8
                for (int kk = 0; kk < 64; kk++) acc += iv[kk] * rr[kk];
                Ab[ia_next][b * 68 + p] = acc;
            }
        } else if (w < 2) {
            // a_next = r/3 + r @ S^T, r hi/lo bf16, S bf16 frags (waves 0,1)
            int m = w * 16 + nr;        // this wave's mtile = w
            bf16x8 rhi[2], rlo[2];
            #pragma unroll
            for (int kt = 0; kt < 2; kt++) {
                us8 hv, lv;
                #pragma unroll
                for (int j = 0; j < 8; j++) {
                    float x = rbuf[m * 68 + kt * 32 + c0 + j];
                    unsigned short h = f2bf(x);
                    hv[j] = h;
                    lv[j] = f2bf(x - bf2f(h));
                }
                rhi[kt] = __builtin_bit_cast(bf16x8, hv);
                rlo[kt] = __builtin_bit_cast(bf16x8, lv);
            }
            int col = l & 15, q = l >> 4;
            #pragma unroll
            for (int pt = 0; pt < 4; pt++) {
                f32x4 acc;
                #pragma unroll
                for (int r = 0; r < 4; r++)
                    acc[r] = rbuf[(w * 16 + q * 4 + r) * 68 + pt * 16 + col] * (1.0f / 3.0f);
                #pragma unroll
                for (int kt = 0; kt < 2; kt++) {
                    acc = __builtin_amdgcn_mfma_f32_16x16x32_bf16(rhi[kt], sf[pt][kt], acc, 0, 0, 0);
                    acc = __builtin_amdgcn_mfma_f32_16x16x32_bf16(rlo[kt], sf[pt][kt], acc, 0, 0, 0);
                }
                #pragma unroll
                for (int r = 0; r < 4; r++)
                    Ab[ia_next][(w * 16 + q * 4 + r) * 68 + pt * 16 + col] = acc[r];
            }
        }
        __syncthreads();

        if (k == NSTEP - 1 && blk == 0) {
            for (int i = t; i < 2048; i += 512)
                out[i] = (Ab[ia_next][(i >> 6) * 68 + (i & 63)] - state[i]) * INV_DT_SKIP;
        }

        int tmp = ia_prev; ia_prev = ia_cur; ia_cur = ia_next; ia_next = tmp;
        ifc ^= 1;
    }
}

// ---------------------------------------------------------------------------
extern "C" void kernel_launch(void* const* d_in, const int* in_sizes, int n_in,
                              void* d_out, int out_size, void* d_ws, size_t ws_size,
                              hipStream_t stream) {
    const float* state = (const float*)d_in[0];   // (32, 64)
    const float* Ap    = (const float*)d_in[1];   // (64, 64)
    const float* Wu    = (const float*)d_in[2];   // (32000, 64)
    const float* Wv    = (const float*)d_in[3];   // (32000, 64)
    const float* Pp    = (const float*)d_in[4];   // (64, 16000)
    float* out = (float*)d_out;
    float* ws  = (float*)d_ws;

    float* inv1 = ws;                         // 4096 floats
    float* inv2 = ws + 4096;                  // 4096 floats
    float* F    = ws + 8192;                  // 3 * 2048 floats
    unsigned* cnt = (unsigned*)(ws + 8192 + 3 * 2048);

    hipLaunchKernelGGL(kzero, dim3(1), dim3(256), 0, stream, F, cnt);
    hipLaunchKernelGGL(kinv, dim3(2), dim3(256), 0, stream, Ap, inv1, inv2);
    hipLaunchKernelGGL(kmain, dim3(NBLK), dim3(512), 0, stream,
                       state, Wu, Wv, Pp, inv1, inv2, F, cnt, out);
}

// Round 4
// 1913.089 us; speedup vs baseline: 1.3992x; 1.3992x over previous
//
#include <hip/hip_runtime.h>

#define DTC 0.02f
#define INV_DT_SKIP 2.5f            // 1/(0.02*20)
#define NBLK 250
#define NSTEP 50

typedef __attribute__((ext_vector_type(8))) __bf16 bf16x8;
typedef __attribute__((ext_vector_type(4))) float f32x4;
typedef __attribute__((ext_vector_type(8))) unsigned short us8;

__device__ inline unsigned short f2bf(float x) {        // RNE fp32->bf16
    unsigned u = __float_as_uint(x);
    unsigned r = u + 0x7FFF + ((u >> 16) & 1u);
    return (unsigned short)(r >> 16);
}
__device__ inline float bf2f(unsigned short h) {
    return __uint_as_float(((unsigned)h) << 16);
}
// Agent-scoped (cross-XCD coherent) plain accesses: bypass stale L1/L2,
// execute at the device coherence point. No fences needed anywhere.
__device__ inline float gload(const float* p) {
    return __hip_atomic_load(p, __ATOMIC_RELAXED, __HIP_MEMORY_SCOPE_AGENT);
}
__device__ inline void gstore(float* p, float v) {
    __hip_atomic_store(p, v, __ATOMIC_RELAXED, __HIP_MEMORY_SCOPE_AGENT);
}

// ---------------------------------------------------------------------------
// Neumann inverses (verified rounds 1-3). inv1 = (I-dt*Ap)^-1,
// inv2 = (3I-2dt*Ap)^-1.
// ---------------------------------------------------------------------------
__global__ __launch_bounds__(256) void kinv(const float* __restrict__ Ap,
                                            float* __restrict__ inv1,
                                            float* __restrict__ inv2) {
    const int t = threadIdx.x;
    const float coef  = (blockIdx.x == 0) ? DTC : (2.0f * DTC / 3.0f);
    const float scale = (blockIdx.x == 0) ? 1.0f : (1.0f / 3.0f);
    float* outp = (blockIdx.x == 0) ? inv1 : inv2;

    __shared__ float ET[64 * 68];
    __shared__ float XA[64 * 68];
    __shared__ float XB[64 * 68];

    for (int idx = t; idx < 4096; idx += 256) {
        int r = idx >> 6, c = idx & 63;
        float e = coef * Ap[idx];
        ET[c * 68 + r] = e;
        XA[r * 68 + c] = ((r == c) ? 1.0f : 0.0f) + e;
    }
    __syncthreads();

    const int rr = (t >> 4) << 2;
    const int cc = (t & 15) << 2;
    float* bufs[2] = {XA, XB};
    for (int it = 0; it < 3; it++) {
        const float* Xin = bufs[it & 1];
        float* Xout = bufs[(it + 1) & 1];
        float acc[4][4];
        #pragma unroll
        for (int i = 0; i < 4; i++)
            #pragma unroll
            for (int j = 0; j < 4; j++)
                acc[i][j] = ((rr + i) == (cc + j)) ? 1.0f : 0.0f;
        for (int k = 0; k < 64; k++) {
            float4 e4 = *(const float4*)&ET[k * 68 + rr];
            float4 x4 = *(const float4*)&Xin[k * 68 + cc];
            float ev[4] = {e4.x, e4.y, e4.z, e4.w};
            float xv[4] = {x4.x, x4.y, x4.z, x4.w};
            #pragma unroll
            for (int i = 0; i < 4; i++)
                #pragma unroll
                for (int j = 0; j < 4; j++)
                    acc[i][j] += ev[i] * xv[j];
        }
        __syncthreads();
        #pragma unroll
        for (int i = 0; i < 4; i++)
            #pragma unroll
            for (int j = 0; j < 4; j++)
                Xout[(rr + i) * 68 + cc + j] = acc[i][j];
        __syncthreads();
    }
    const float* Xf = bufs[1];
    for (int idx = t; idx < 4096; idx += 256) {
        int r = idx >> 6, c = idx & 63;
        outp[idx] = scale * Xf[r * 68 + c];
    }
}

// ---------------------------------------------------------------------------
// Zero the grid-barrier counter (ws is poisoned 0xAA before every launch).
// ---------------------------------------------------------------------------
__global__ void kzero(unsigned* __restrict__ cnt) {
    if (threadIdx.x == 0) *cnt = 0u;
}

// ---------------------------------------------------------------------------
// Lean monotone-counter grid barrier. All NBLK blocks resident (LDS 116KB ->
// 1 block/CU, 250 <= 256 CUs; co-residency verified empirically round 3).
// __syncthreads drains vmcnt for the whole block (m97: full s_waitcnt before
// s_barrier), so the leader's RELEASE add publishes after all block stores
// completed. No cache fences: all cross-block data uses agent-scoped ops.
// ---------------------------------------------------------------------------
__device__ inline void gridbar(unsigned* cnt, unsigned target) {
    __syncthreads();
    if (threadIdx.x == 0) {
        __hip_atomic_fetch_add(cnt, 1u, __ATOMIC_RELEASE, __HIP_MEMORY_SCOPE_AGENT);
        while (__hip_atomic_load(cnt, __ATOMIC_ACQUIRE, __HIP_MEMORY_SCOPE_AGENT) < target)
            __builtin_amdgcn_s_sleep(8);
    }
    __syncthreads();
}

// ---------------------------------------------------------------------------
// Persistent kernel: all 50 steps, two grid barriers per step, zero atomics
// on data.
//   Phase A (verified): z = a@W^T hi/lo bf16 MFMA from register-resident W
//   frags, f = u*dx+v*dy, LDS C->A relayout, proj MFMA vs register P frags,
//   block LDS reduce -> private partial slot (agent stores, contention-free).
//   bar1.
//   Reduce: block j sums column-group j (8 cols) over 250 partials (agent
//   loads, shuffle-reduce), stores negated f. Blocks 0..5 also do groups
//   250..255. bar2.
//   Phase B (verified, redundant per block): read f (agent), BDF2 r,
//   a_next = r/3 + r@S^T hi/lo MFMA (S = inv2 - I/3); step 0 fp32 matvec
//   with inv1. Block 0 writes output at the last step.
// ---------------------------------------------------------------------------
__global__ __launch_bounds__(512, 2)
void kmain(const float* __restrict__ state,
           const float* __restrict__ Wu,
           const float* __restrict__ Wv,
           const float* __restrict__ Pp,
           const float* __restrict__ inv1,
           const float* __restrict__ inv2,
           float* __restrict__ partials,
           float* __restrict__ fglob,
           unsigned* __restrict__ cnt,
           float* __restrict__ out) {
    const int t = threadIdx.x;
    const int l = t & 63;
    const int w = t >> 6;                 // wave 0..7
    const int blk = blockIdx.x;

    __shared__ float Ab[3][2176];         // a triple buffer, 32 rows x 68
    __shared__ float fb[8][16][36];       // per-wave f tile (K=32, zero-padded)
    __shared__ float red[8][1024];        // per-wave proj partials
    __shared__ float invL[64 * 65];       // inv1 for step-0 fp32 matvec
    __shared__ float fpp[2][2048];        // f ping-pong (f_cur / f_prev)
    __shared__ float rbuf[32 * 68];       // r, padded stride 68

    for (int i = t; i < 2048; i += 512) Ab[0][(i >> 6) * 68 + (i & 63)] = state[i];
    for (int i = t; i < 4096; i += 512) invL[(i >> 6) * 65 + (i & 63)] = inv1[i];
    for (int i = t; i < 8 * 16 * 36; i += 512) ((float*)fb)[i] = 0.f;

    // ---- wave tile mapping (verified rounds 2-3) ----
    const int gw = blk * 8 + w;           // 0..1999
    const int tile = gw >> 1;             // 16-group tile 0..999
    const int mt = gw & 1;                // batch mtile
    const int net = tile >= 500;
    const int tn = net ? tile - 500 : tile;
    const int half = tile & 1;
    const int gc = tile >> 1;
    const float* W = net ? Wv : Wu;
    const int nr = l & 15;
    const int c0 = (l >> 4) << 3;

    // ---- preload all fragments into registers (held across the loop) ----
    bf16x8 wf[4][2], pf[4], sf[4][2];
    #pragma unroll
    for (int rb = 0; rb < 4; rb++)
        #pragma unroll
        for (int kt = 0; kt < 2; kt++) {
            const float* s = W + (size_t)(rb * 8000 + tn * 16 + nr) * 64 + kt * 32 + c0;
            us8 o;
            #pragma unroll
            for (int j = 0; j < 8; j++) o[j] = f2bf(s[j]);
            wf[rb][kt] = __builtin_bit_cast(bf16x8, o);
        }
    #pragma unroll
    for (int pt = 0; pt < 4; pt++) {
        const float* s = Pp + (size_t)(pt * 16 + nr) * 16000 + gc * 32 + c0;
        us8 o;
        #pragma unroll
        for (int j = 0; j < 8; j++) o[j] = f2bf(s[j]);
        pf[pt] = __builtin_bit_cast(bf16x8, o);
    }
    #pragma unroll
    for (int pt = 0; pt < 4; pt++)          // S = inv2 - I/3 (B-frag layout)
        #pragma unroll
        for (int kt = 0; kt < 2; kt++) {
            int p = pt * 16 + nr;
            const float* s = inv2 + (size_t)p * 64 + kt * 32 + c0;
            us8 o;
            #pragma unroll
            for (int j = 0; j < 8; j++) {
                float v = s[j] - ((p == kt * 32 + c0 + j) ? (1.0f / 3.0f) : 0.0f);
                o[j] = f2bf(v);
            }
            sf[pt][kt] = __builtin_bit_cast(bf16x8, o);
        }
    __syncthreads();

    int ia_prev = 2, ia_cur = 0, ia_next = 1;
    int ifc = 0;

    for (int k = 0; k < NSTEP; k++) {
        // ================= phase A: rhs partials =================
        bf16x8 ahi[2], alo[2];
        {
            const float* ac = Ab[ia_cur];
            int m = mt * 16 + nr;
            #pragma unroll
            for (int kt = 0; kt < 2; kt++) {
                us8 hv, lv;
                #pragma unroll
                for (int j = 0; j < 8; j++) {
                    float x = ac[m * 68 + kt * 32 + c0 + j];
                    unsigned short h = f2bf(x);
                    hv[j] = h;
                    lv[j] = f2bf(x - bf2f(h));
                }
                ahi[kt] = __builtin_bit_cast(bf16x8, hv);
                alo[kt] = __builtin_bit_cast(bf16x8, lv);
            }
        }

        f32x4 z[4];
        #pragma unroll
        for (int rb = 0; rb < 4; rb++) {
            f32x4 acc = {0.f, 0.f, 0.f, 0.f};
            #pragma unroll
            for (int kt = 0; kt < 2; kt++) {
                acc = __builtin_amdgcn_mfma_f32_16x16x32_bf16(ahi[kt], wf[rb][kt], acc, 0, 0, 0);
                acc = __builtin_amdgcn_mfma_f32_16x16x32_bf16(alo[kt], wf[rb][kt], acc, 0, 0, 0);
            }
            z[rb] = acc;
        }

        {
            int col = l & 15, q = l >> 4;
            #pragma unroll
            for (int r = 0; r < 4; r++) {
                float f = z[0][r] * z[2][r] + z[1][r] * z[3][r];
                fb[w][q * 4 + r][half * 16 + col] = f;
            }
        }
        __syncthreads();

        bf16x8 ff;
        {
            us8 fv;
            #pragma unroll
            for (int j = 0; j < 8; j++) fv[j] = f2bf(fb[w][nr][c0 + j]);
            ff = __builtin_bit_cast(bf16x8, fv);
        }

        {
            int col = l & 15, q = l >> 4;
            #pragma unroll
            for (int pt = 0; pt < 4; pt++) {
                f32x4 r2 = {0.f, 0.f, 0.f, 0.f};
                r2 = __builtin_amdgcn_mfma_f32_16x16x32_bf16(ff, pf[pt], r2, 0, 0, 0);
                #pragma unroll
                for (int r = 0; r < 4; r++)
                    red[w][(q * 4 + r) * 64 + pt * 16 + col] = r2[r];
            }
        }
        __syncthreads();

        // private partial slot: contention-free agent stores (coalesced)
        for (int i = t; i < 2048; i += 512) {
            int b = i >> 6, p = i & 63;
            int mtb = b >> 4, bl = b & 15;
            float s = red[0 + mtb][bl * 64 + p] + red[2 + mtb][bl * 64 + p]
                    + red[4 + mtb][bl * 64 + p] + red[6 + mtb][bl * 64 + p];
            gstore(&partials[(size_t)blk * 2048 + i], s);
        }

        gridbar(cnt, (unsigned)(NBLK * (2 * k + 1)));

        // ================= reduce: f = -sum_m partials[m] =================
        for (int g = blk; g < 256; g += NBLK) {
            int col = g * 8 + w;                 // wave w owns one column
            float s = 0.f;
            #pragma unroll
            for (int j = 0; j < 4; j++) {
                int m = l + j * 64;
                if (m < NBLK) s += gload(&partials[(size_t)m * 2048 + col]);
            }
            #pragma unroll
            for (int off = 32; off >= 1; off >>= 1)
                s += __shfl_down(s, off);
            if (l == 0) gstore(&fglob[col], -s);
        }

        gridbar(cnt, (unsigned)(NBLK * (2 * k + 2)));

        // ================= phase B: update (redundant per block) =================
        float* fc = fpp[ifc];
        const float* fp = fpp[ifc ^ 1];
        for (int i = t; i < 2048; i += 512) {
            float f = gload(&fglob[i]);
            fc[i] = f;
            int row = (i >> 6) * 68 + (i & 63);
            float av = Ab[ia_cur][row];
            float rv = (k == 0) ? (av + DTC * f)
                                : (4.f * av - Ab[ia_prev][row]
                                   + 4.f * DTC * f - 2.f * DTC * fp[i]);
            rbuf[row] = rv;
        }
        __syncthreads();

        if (k == 0) {
            int p = t & 63;
            int b0 = (t >> 6) * 4;
            #pragma unroll
            for (int j = 0; j < 4; j++) {
                int b = b0 + j;
                float acc = 0.f;
                const float* iv = &invL[p * 65];
                const float* rr = &rbuf[b * 68];
                #pragma unroll 8
                for (int kk = 0; kk < 64; kk++) acc += iv[kk] * rr[kk];
                Ab[ia_next][b * 68 + p] = acc;
            }
        } else if (w < 2) {
            int m = w * 16 + nr;
            bf16x8 rhi[2], rlo[2];
            #pragma unroll
            for (int kt = 0; kt < 2; kt++) {
                us8 hv, lv;
                #pragma unroll
                for (int j = 0; j < 8; j++) {
                    float x = rbuf[m * 68 + kt * 32 + c0 + j];
                    unsigned short h = f2bf(x);
                    hv[j] = h;
                    lv[j] = f2bf(x - bf2f(h));
                }
                rhi[kt] = __builtin_bit_cast(bf16x8, hv);
                rlo[kt] = __builtin_bit_cast(bf16x8, lv);
            }
            int col = l & 15, q = l >> 4;
            #pragma unroll
            for (int pt = 0; pt < 4; pt++) {
                f32x4 acc;
                #pragma unroll
                for (int r = 0; r < 4; r++)
                    acc[r] = rbuf[(w * 16 + q * 4 + r) * 68 + pt * 16 + col] * (1.0f / 3.0f);
                #pragma unroll
                for (int kt = 0; kt < 2; kt++) {
                    acc = __builtin_amdgcn_mfma_f32_16x16x32_bf16(rhi[kt], sf[pt][kt], acc, 0, 0, 0);
                    acc = __builtin_amdgcn_mfma_f32_16x16x32_bf16(rlo[kt], sf[pt][kt], acc, 0, 0, 0);
                }
                #pragma unroll
                for (int r = 0; r < 4; r++)
                    Ab[ia_next][(w * 16 + q * 4 + r) * 68 + pt * 16 + col] = acc[r];
            }
        }
        __syncthreads();

        if (k == NSTEP - 1 && blk == 0) {
            for (int i = t; i < 2048; i += 512)
                out[i] = (Ab[ia_next][(i >> 6) * 68 + (i & 63)] - state[i]) * INV_DT_SKIP;
        }

        int tmp = ia_prev; ia_prev = ia_cur; ia_cur = ia_next; ia_next = tmp;
        ifc ^= 1;
    }
}

// ---------------------------------------------------------------------------
extern "C" void kernel_launch(void* const* d_in, const int* in_sizes, int n_in,
                              void* d_out, int out_size, void* d_ws, size_t ws_size,
                              hipStream_t stream) {
    const float* state = (const float*)d_in[0];   // (32, 64)
    const float* Ap    = (const float*)d_in[1];   // (64, 64)
    const float* Wu    = (const float*)d_in[2];   // (32000, 64)
    const float* Wv    = (const float*)d_in[3];   // (32000, 64)
    const float* Pp    = (const float*)d_in[4];   // (64, 16000)
    float* out = (float*)d_out;
    float* ws  = (float*)d_ws;

    float* inv1  = ws;                        // 4096 floats
    float* inv2  = ws + 4096;                 // 4096 floats
    float* fglob = ws + 8192;                 // 2048 floats
    unsigned* cnt = (unsigned*)(ws + 10240);
    float* partials = ws + 12288;             // 250 * 2048 floats

    hipLaunchKernelGGL(kzero, dim3(1), dim3(64), 0, stream, cnt);
    hipLaunchKernelGGL(kinv, dim3(2), dim3(256), 0, stream, Ap, inv1, inv2);
    hipLaunchKernelGGL(kmain, dim3(NBLK), dim3(512), 0, stream,
                       state, Wu, Wv, Pp, inv1, inv2, partials, fglob, cnt, out);
}

// Round 5
// 620.698 us; speedup vs baseline: 4.3125x; 3.0822x over previous
//
#include <hip/hip_runtime.h>

#define DTC 0.02f
#define INV_DT_SKIP 2.5f            // 1/(0.02*20)
#define NBLK 64
#define NSTEP 50
#define NACT 500                    // active waves = 32-group chunks

typedef __attribute__((ext_vector_type(8))) __bf16 bf16x8;
typedef __attribute__((ext_vector_type(4))) float f32x4;
typedef __attribute__((ext_vector_type(8))) unsigned short us8;
typedef unsigned long long u64t;

__device__ inline unsigned short f2bf(float x) {        // RNE fp32->bf16
    unsigned u = __float_as_uint(x);
    unsigned r = u + 0x7FFF + ((u >> 16) & 1u);
    return (unsigned short)(r >> 16);
}
__device__ inline float bf2f(unsigned short h) {
    return __uint_as_float(((unsigned)h) << 16);
}
__device__ inline unsigned pack2(float a, float b) {
    return (unsigned)f2bf(a) | ((unsigned)f2bf(b) << 16);
}
// Agent-scoped (cross-XCD coherent) accesses for all cross-block data.
__device__ inline void gstore32(unsigned* p, unsigned v) {
    __hip_atomic_store(p, v, __ATOMIC_RELAXED, __HIP_MEMORY_SCOPE_AGENT);
}
__device__ inline u64t gload64(const u64t* p) {
    return __hip_atomic_load(p, __ATOMIC_RELAXED, __HIP_MEMORY_SCOPE_AGENT);
}
__device__ inline void gstore64(u64t* p, u64t v) {
    __hip_atomic_store(p, v, __ATOMIC_RELAXED, __HIP_MEMORY_SCOPE_AGENT);
}

// ---------------------------------------------------------------------------
// Neumann inverses (verified rounds 1-4). inv1 = (I-dt*Ap)^-1,
// inv2 = (3I-2dt*Ap)^-1.
// ---------------------------------------------------------------------------
__global__ __launch_bounds__(256) void kinv(const float* __restrict__ Ap,
                                            float* __restrict__ inv1,
                                            float* __restrict__ inv2) {
    const int t = threadIdx.x;
    const float coef  = (blockIdx.x == 0) ? DTC : (2.0f * DTC / 3.0f);
    const float scale = (blockIdx.x == 0) ? 1.0f : (1.0f / 3.0f);
    float* outp = (blockIdx.x == 0) ? inv1 : inv2;

    __shared__ float ET[64 * 68];
    __shared__ float XA[64 * 68];
    __shared__ float XB[64 * 68];

    for (int idx = t; idx < 4096; idx += 256) {
        int r = idx >> 6, c = idx & 63;
        float e = coef * Ap[idx];
        ET[c * 68 + r] = e;
        XA[r * 68 + c] = ((r == c) ? 1.0f : 0.0f) + e;
    }
    __syncthreads();

    const int rr = (t >> 4) << 2;
    const int cc = (t & 15) << 2;
    float* bufs[2] = {XA, XB};
    for (int it = 0; it < 3; it++) {
        const float* Xin = bufs[it & 1];
        float* Xout = bufs[(it + 1) & 1];
        float acc[4][4];
        #pragma unroll
        for (int i = 0; i < 4; i++)
            #pragma unroll
            for (int j = 0; j < 4; j++)
                acc[i][j] = ((rr + i) == (cc + j)) ? 1.0f : 0.0f;
        for (int k = 0; k < 64; k++) {
            float4 e4 = *(const float4*)&ET[k * 68 + rr];
            float4 x4 = *(const float4*)&Xin[k * 68 + cc];
            float ev[4] = {e4.x, e4.y, e4.z, e4.w};
            float xv[4] = {x4.x, x4.y, x4.z, x4.w};
            #pragma unroll
            for (int i = 0; i < 4; i++)
                #pragma unroll
                for (int j = 0; j < 4; j++)
                    acc[i][j] += ev[i] * xv[j];
        }
        __syncthreads();
        #pragma unroll
        for (int i = 0; i < 4; i++)
            #pragma unroll
            for (int j = 0; j < 4; j++)
                Xout[(rr + i) * 68 + cc + j] = acc[i][j];
        __syncthreads();
    }
    const float* Xf = bufs[1];
    for (int idx = t; idx < 4096; idx += 256) {
        int r = idx >> 6, c = idx & 63;
        outp[idx] = scale * Xf[r * 68 + c];
    }
}

__global__ void kzero(unsigned* __restrict__ cnt) {
    if (threadIdx.x == 0) *cnt = 0u;
}

// ---------------------------------------------------------------------------
// Lean monotone-counter grid barrier; 64 resident blocks (LDS 118KB ->
// 1 block/CU). __syncthreads drains all outstanding memory ops before the
// leader's RELEASE arrival. All cross-block data is agent-scoped.
// ---------------------------------------------------------------------------
__device__ inline void gridbar(unsigned* cnt, unsigned target) {
    __syncthreads();
    if (threadIdx.x == 0) {
        __hip_atomic_fetch_add(cnt, 1u, __ATOMIC_RELEASE, __HIP_MEMORY_SCOPE_AGENT);
        while (__hip_atomic_load(cnt, __ATOMIC_ACQUIRE, __HIP_MEMORY_SCOPE_AGENT) < target)
            __builtin_amdgcn_s_sleep(4);
    }
    __syncthreads();
}

// ---------------------------------------------------------------------------
// Persistent kernel, 64 blocks, 2 barriers/step, bf16-packed communication.
// Wave q = blk*8+w (q<500 active) owns 32-group chunk q: both K-halves of
// one P chunk -> one full-K proj MFMA per (mt,pt). All W/P/S fragments
// register-resident. Per-step cross-block traffic: 64 x 4KB partial (u32
// bf16-pairs) + line-efficient gather + 4KB f broadcast = 0.77 MB.
// ---------------------------------------------------------------------------
__global__ __launch_bounds__(512, 2)
void kmain(const float* __restrict__ state,
           const float* __restrict__ Wu,
           const float* __restrict__ Wv,
           const float* __restrict__ Pp,
           const float* __restrict__ inv1,
           const float* __restrict__ inv2,
           unsigned* __restrict__ pbuf,     // 64 slots x 1024 u32 (2048 bf16)
           u64t* __restrict__ fg,           // 512 u64 = 2048 bf16 (negated f)
           unsigned* __restrict__ cnt,
           float* __restrict__ out) {
    const int t = threadIdx.x;
    const int l = t & 63;
    const int w = t >> 6;                 // wave 0..7
    const int blk = blockIdx.x;
    const int q = blk * 8 + w;            // global wave = group chunk
    const bool active = (q < NACT);

    __shared__ float Ab[3][2176];         // a triple buffer, 32 rows x 68
    __shared__ float fb[8][2][16][36];    // per-wave f tile [mt][16b][K=32+pad]
    __shared__ float red[8][1024];        // per-wave proj partials (16b x 64p)
    __shared__ float fpp[2][2048];        // f ping-pong (fp32, from bf16 f)
    __shared__ float rbuf[32 * 68];       // r, padded stride 68

    for (int i = t; i < 2048; i += 512) Ab[0][(i >> 6) * 68 + (i & 63)] = state[i];
    for (int i = t; i < 8192; i += 512) ((float*)red)[i] = 0.f;   // inactive waves stay 0

    const int nr = l & 15;
    const int c0 = (l >> 4) << 3;
    const float* W = (q < 250) ? Wu : Wv;
    const int gl0 = ((q < 250) ? q : q - 250) * 32;   // net-local group base

    // ---- register-resident fragments ----
    bf16x8 wf[2][4][2], pf[4], sf[4][2];
    if (active) {
        #pragma unroll
        for (int th = 0; th < 2; th++)
            #pragma unroll
            for (int rb = 0; rb < 4; rb++)
                #pragma unroll
                for (int kt = 0; kt < 2; kt++) {
                    const float* s = W + (size_t)(rb * 8000 + gl0 + th * 16 + nr) * 64 + kt * 32 + c0;
                    us8 o;
                    #pragma unroll
                    for (int j = 0; j < 8; j++) o[j] = f2bf(s[j]);
                    wf[th][rb][kt] = __builtin_bit_cast(bf16x8, o);
                }
        #pragma unroll
        for (int pt = 0; pt < 4; pt++) {
            const float* s = Pp + (size_t)(pt * 16 + nr) * 16000 + q * 32 + c0;
            us8 o;
            #pragma unroll
            for (int j = 0; j < 8; j++) o[j] = f2bf(s[j]);
            pf[pt] = __builtin_bit_cast(bf16x8, o);
        }
    }
    if (w < 2) {                            // S = inv2 - I/3 (B-frag layout)
        #pragma unroll
        for (int pt = 0; pt < 4; pt++)
            #pragma unroll
            for (int kt = 0; kt < 2; kt++) {
                int p = pt * 16 + nr;
                const float* s = inv2 + (size_t)p * 64 + kt * 32 + c0;
                us8 o;
                #pragma unroll
                for (int j = 0; j < 8; j++) {
                    float v = s[j] - ((p == kt * 32 + c0 + j) ? (1.0f / 3.0f) : 0.0f);
                    o[j] = f2bf(v);
                }
                sf[pt][kt] = __builtin_bit_cast(bf16x8, o);
            }
    }
    __syncthreads();

    int ia_prev = 2, ia_cur = 0, ia_next = 1;
    int ifc = 0;

    for (int k = 0; k < NSTEP; k++) {
        // ================= phase A: rhs partials =================
        if (active) {
            bf16x8 ahi[2][2], alo[2][2];
            const float* ac = Ab[ia_cur];
            #pragma unroll
            for (int mt = 0; mt < 2; mt++)
                #pragma unroll
                for (int kt = 0; kt < 2; kt++) {
                    us8 hv, lv;
                    #pragma unroll
                    for (int j = 0; j < 8; j++) {
                        float x = ac[(mt * 16 + nr) * 68 + kt * 32 + c0 + j];
                        unsigned short h = f2bf(x);
                        hv[j] = h;
                        lv[j] = f2bf(x - bf2f(h));
                    }
                    ahi[mt][kt] = __builtin_bit_cast(bf16x8, hv);
                    alo[mt][kt] = __builtin_bit_cast(bf16x8, lv);
                }
            const int col = l & 15, q4 = l >> 4;
            #pragma unroll
            for (int mt = 0; mt < 2; mt++)
                #pragma unroll
                for (int th = 0; th < 2; th++) {
                    f32x4 z[4];
                    #pragma unroll
                    for (int rb = 0; rb < 4; rb++) {
                        f32x4 acc = {0.f, 0.f, 0.f, 0.f};
                        #pragma unroll
                        for (int kt = 0; kt < 2; kt++) {
                            acc = __builtin_amdgcn_mfma_f32_16x16x32_bf16(ahi[mt][kt], wf[th][rb][kt], acc, 0, 0, 0);
                            acc = __builtin_amdgcn_mfma_f32_16x16x32_bf16(alo[mt][kt], wf[th][rb][kt], acc, 0, 0, 0);
                        }
                        z[rb] = acc;
                    }
                    #pragma unroll
                    for (int r = 0; r < 4; r++) {
                        float f = z[0][r] * z[2][r] + z[1][r] * z[3][r];
                        fb[w][mt][q4 * 4 + r][th * 16 + col] = f;
                    }
                }
        }
        __syncthreads();

        bf16x8 ff[2];
        if (active) {
            #pragma unroll
            for (int mt = 0; mt < 2; mt++) {
                us8 fv;
                #pragma unroll
                for (int j = 0; j < 8; j++) fv[j] = f2bf(fb[w][mt][nr][c0 + j]);
                ff[mt] = __builtin_bit_cast(bf16x8, fv);
            }
        }

        #pragma unroll
        for (int mt = 0; mt < 2; mt++) {
            if (active) {
                const int col = l & 15, q4 = l >> 4;
                #pragma unroll
                for (int pt = 0; pt < 4; pt++) {
                    f32x4 rc = {0.f, 0.f, 0.f, 0.f};
                    rc = __builtin_amdgcn_mfma_f32_16x16x32_bf16(ff[mt], pf[pt], rc, 0, 0, 0);
                    #pragma unroll
                    for (int r = 0; r < 4; r++)
                        red[w][(q4 * 4 + r) * 64 + pt * 16 + col] = rc[r];
                }
            }
            __syncthreads();
            {   // block partial (1024 elems this mt) -> packed bf16 pairs
                float s0 = 0.f, s1 = 0.f;
                #pragma unroll
                for (int w8 = 0; w8 < 8; w8++) {
                    s0 += red[w8][2 * t];
                    s1 += red[w8][2 * t + 1];
                }
                gstore32(&pbuf[blk * 1024 + mt * 512 + t], pack2(s0, s1));
            }
            __syncthreads();
        }

        gridbar(cnt, (unsigned)(NBLK * (2 * k + 1)));

        // ============ reduce: block blk owns f-elems [32*blk, 32*blk+32) ============
        {
            u64t v = gload64((const u64t*)pbuf + (size_t)l * 512 + blk * 8 + w);
            float s0 = bf2f((unsigned short)(v & 0xffff));
            float s1 = bf2f((unsigned short)((v >> 16) & 0xffff));
            float s2 = bf2f((unsigned short)((v >> 32) & 0xffff));
            float s3 = bf2f((unsigned short)(v >> 48));
            #pragma unroll
            for (int off = 32; off >= 1; off >>= 1) {
                s0 += __shfl_down(s0, off);
                s1 += __shfl_down(s1, off);
                s2 += __shfl_down(s2, off);
                s3 += __shfl_down(s3, off);
            }
            if (l == 0) {
                u64t pv = (u64t)pack2(-s0, -s1) | ((u64t)pack2(-s2, -s3) << 32);
                gstore64(&fg[blk * 8 + w], pv);
            }
        }

        gridbar(cnt, (unsigned)(NBLK * (2 * k + 2)));

        // ================= phase B: update (redundant per block) =================
        {
            u64t v = gload64(&fg[t]);          // f-elems 4t..4t+3 (already negated)
            float fv[4] = { bf2f((unsigned short)(v & 0xffff)),
                            bf2f((unsigned short)((v >> 16) & 0xffff)),
                            bf2f((unsigned short)((v >> 32) & 0xffff)),
                            bf2f((unsigned short)(v >> 48)) };
            const int b = (4 * t) >> 6, p0 = (4 * t) & 63;
            float* fc = fpp[ifc];
            const float* fp = fpp[ifc ^ 1];
            #pragma unroll
            for (int jj = 0; jj < 4; jj++) {
                int i = 4 * t + jj;
                float f = fv[jj];
                fc[i] = f;
                int row = b * 68 + p0 + jj;
                float av = Ab[ia_cur][row];
                float rv = (k == 0) ? (av + DTC * f)
                                    : (4.f * av - Ab[ia_prev][row]
                                       + 4.f * DTC * f - 2.f * DTC * fp[i]);
                rbuf[row] = rv;
            }
        }
        __syncthreads();

        if (w < 2) {
            // a_next = cbase*r + r @ S^T (r hi/lo bf16; verified round 4)
            auto solve = [&](const bf16x8 (&S)[4][2], float cbase) {
                int m = w * 16 + nr;
                bf16x8 rhi[2], rlo[2];
                #pragma unroll
                for (int kt = 0; kt < 2; kt++) {
                    us8 hv, lv;
                    #pragma unroll
                    for (int j = 0; j < 8; j++) {
                        float x = rbuf[m * 68 + kt * 32 + c0 + j];
                        unsigned short h = f2bf(x);
                        hv[j] = h;
                        lv[j] = f2bf(x - bf2f(h));
                    }
                    rhi[kt] = __builtin_bit_cast(bf16x8, hv);
                    rlo[kt] = __builtin_bit_cast(bf16x8, lv);
                }
                int col = l & 15, q4 = l >> 4;
                #pragma unroll
                for (int pt = 0; pt < 4; pt++) {
                    f32x4 acc;
                    #pragma unroll
                    for (int r = 0; r < 4; r++)
                        acc[r] = rbuf[(w * 16 + q4 * 4 + r) * 68 + pt * 16 + col] * cbase;
                    #pragma unroll
                    for (int kt = 0; kt < 2; kt++) {
                        acc = __builtin_amdgcn_mfma_f32_16x16x32_bf16(rhi[kt], S[pt][kt], acc, 0, 0, 0);
                        acc = __builtin_amdgcn_mfma_f32_16x16x32_bf16(rlo[kt], S[pt][kt], acc, 0, 0, 0);
                    }
                    #pragma unroll
                    for (int r = 0; r < 4; r++)
                        Ab[ia_next][(w * 16 + q4 * 4 + r) * 68 + pt * 16 + col] = acc[r];
                }
            };
            if (k == 0) {
                bf16x8 s1f[4][2];               // S1 = inv1 - I, built once
                #pragma unroll
                for (int pt = 0; pt < 4; pt++)
                    #pragma unroll
                    for (int kt = 0; kt < 2; kt++) {
                        int p = pt * 16 + nr;
                        const float* s = inv1 + (size_t)p * 64 + kt * 32 + c0;
                        us8 o;
                        #pragma unroll
                        for (int j = 0; j < 8; j++) {
                            float v = s[j] - ((p == kt * 32 + c0 + j) ? 1.0f : 0.0f);
                            o[j] = f2bf(v);
                        }
                        s1f[pt][kt] = __builtin_bit_cast(bf16x8, o);
                    }
                solve(s1f, 1.0f);
            } else {
                solve(sf, 1.0f / 3.0f);
            }
        }
        __syncthreads();

        if (k == NSTEP - 1 && blk == 0) {
            for (int i = t; i < 2048; i += 512)
                out[i] = (Ab[ia_next][(i >> 6) * 68 + (i & 63)] - state[i]) * INV_DT_SKIP;
        }

        int tmp = ia_prev; ia_prev = ia_cur; ia_cur = ia_next; ia_next = tmp;
        ifc ^= 1;
    }
}

// ---------------------------------------------------------------------------
extern "C" void kernel_launch(void* const* d_in, const int* in_sizes, int n_in,
                              void* d_out, int out_size, void* d_ws, size_t ws_size,
                              hipStream_t stream) {
    const float* state = (const float*)d_in[0];   // (32, 64)
    const float* Ap    = (const float*)d_in[1];   // (64, 64)
    const float* Wu    = (const float*)d_in[2];   // (32000, 64)
    const float* Wv    = (const float*)d_in[3];   // (32000, 64)
    const float* Pp    = (const float*)d_in[4];   // (64, 16000)
    float* out = (float*)d_out;
    float* ws  = (float*)d_ws;

    float* inv1 = ws;                               // 4096 floats
    float* inv2 = ws + 4096;                        // 4096 floats
    unsigned* cnt = (unsigned*)(ws + 8192);         // 16-float pad
    u64t* fg = (u64t*)(ws + 8192 + 16);             // 512 u64 = 1024 floats
    unsigned* pbuf = (unsigned*)(ws + 8192 + 16 + 1024);  // 64 x 1024 u32

    hipLaunchKernelGGL(kzero, dim3(1), dim3(64), 0, stream, cnt);
    hipLaunchKernelGGL(kinv, dim3(2), dim3(256), 0, stream, Ap, inv1, inv2);
    hipLaunchKernelGGL(kmain, dim3(NBLK), dim3(512), 0, stream,
                       state, Wu, Wv, Pp, inv1, inv2, pbuf, fg, cnt, out);
}